// Round 2
// baseline (10956.918 us; speedup 1.0000x reference)
//
#include <hip/hip_runtime.h>
#include <hip/hip_bf16.h>

// ---------------- problem constants ----------------
constexpr int kL = 512;    // sequence length
constexpr int kD = 300;    // embedding dim
constexpr int kM = 300;    // hidden dim
constexpr int NWG = 32;    // workgroups (all co-resident; device barrier group)
constexpr int BLK = 256;   // threads per WG
constexpr int JP = 10;     // h-indices owned per WG (j-slice)
constexpr int NJW = 30;    // WGs that own a j-slice (30*10 = 300)
constexpr int NSPLIT = 6;  // k-splits per gate-row dot
constexpr int KLEN = 50;   // 300 / 6
constexpr int NSL = 16;    // n-slice per WG (32*16 = 512)
constexpr int SEG = 4;     // atomic-accum segmentation (contention reduction)

// ---------------- workspace layout (float offsets; [0] holds the barrier counter) ----------------
constexpr int A_LEMB   = 1024;
constexpr int A_REMB   = A_LEMB   + kL*kD;      // gathered embeddings
constexpr int A_XIOU_L = A_REMB   + kL*kD;      // x@ioux_w.T + ioux_b   [512][900]
constexpr int A_XF_L   = A_XIOU_L + kL*900;     // x@fx_w.T + fx_b       [512][300]
constexpr int A_XIOU_R = A_XF_L   + kL*300;
constexpr int A_XF_R   = A_XIOU_R + kL*900;
constexpr int A_HS_LF  = A_XF_R   + kL*300;     // stage A hidden traces
constexpr int A_HS_LB  = A_HS_LF  + kL*300;
constexpr int A_HS_RF  = A_HS_LB  + kL*300;
constexpr int A_HS_RB  = A_HS_RF  + kL*300;
constexpr int A_HS_L   = A_HS_RB  + kL*300;     // tanh(hs_l_f + hs_l_b[::-1])  (= hmat_l)
constexpr int A_HS_R   = A_HS_L   + kL*300;
constexpr int A_HABUF  = A_HS_R   + kL*300;     // stage A h exchange [2][4][300]
constexpr int A_HBBUF  = A_HABUF  + 2400;       // stage B h_lstm exchange [2][4][300]
constexpr int A_HPACC  = A_HBBUF  + 2400;       // hproj atomic accum [2][SEG][4][300]
constexpr int A_HACC   = A_HPACC  + 9600;       // PV numerator atomic accum [2][SEG][4][300]
constexpr int A_DACC   = A_HACC   + 9600;       // softmax denom slots [2][32][4]
constexpr int A_BFIN   = A_DACC   + 256;        // stage B finals: rh_f1, rh_b1, lh_f2, lh_b2
constexpr int A_END    = A_BFIN   + 1200;       // ~9.94 MB of ws

__device__ __forceinline__ float fsig(float x) { return 1.0f / (1.0f + __expf(-x)); }
__device__ __forceinline__ float ftanh(float x) {
  x = fminf(fmaxf(x, -15.f), 15.f);
  float e = __expf(2.f * x);
  return (e - 1.f) / (e + 1.f);
}

// Device-scope barrier: all NWG workgroups co-resident (grid=32 << 256 CUs).
// syncthreads drains each wave's vmcnt before arrival; release/acquire via
// __threadfence (agent scope) handles cross-XCD visibility.
__device__ __forceinline__ void gbar(unsigned* ctr, int& epoch) {
  __syncthreads();
  if (threadIdx.x == 0) {
    ++epoch;
    __threadfence();
    atomicAdd(ctr, 1u);
    const unsigned tgt = (unsigned)(NWG * epoch);
    while (__hip_atomic_load(ctr, __ATOMIC_RELAXED, __HIP_MEMORY_SCOPE_AGENT) < tgt)
      __builtin_amdgcn_s_sleep(1);
    __threadfence();
  }
  __syncthreads();
}

__global__ __launch_bounds__(BLK) void treelstm_kernel(
    const int* __restrict__ linputs, const int* __restrict__ rinputs,
    const float* __restrict__ emb,
    const float* __restrict__ ioux_w, const float* __restrict__ ioux_b,
    const float* __restrict__ iouh_w, const float* __restrict__ iouh_b,
    const float* __restrict__ fx_w,  const float* __restrict__ fx_b,
    const float* __restrict__ fh_w,  const float* __restrict__ fh_b,
    const float* __restrict__ Wa,    const float* __restrict__ attnh_w,
    const float* __restrict__ attnh_b,
    const float* __restrict__ wh_w,  const float* __restrict__ wh_b,
    const float* __restrict__ wp_w,  const float* __restrict__ wp_b,
    float* __restrict__ ws, float* __restrict__ out) {

  __shared__ __align__(16) float h_lds[4][304];
  __shared__ __align__(16) float hpj_lds[4][304];
  __shared__ __align__(16) float part[4][40][6];
  __shared__ float gv[4][4][10];
  __shared__ float c_lds[4][10];
  __shared__ float hnew_lds[4][10];
  __shared__ __align__(16) float colsum_lds[2][300];
  __shared__ float wa_lds[300];
  __shared__ float sc_lds[4][16];
  __shared__ float red_lds[32];
  __shared__ __align__(16) __hip_bfloat16 hmp_lds[2][NSL][300];   // hm_proj n-slice
  __shared__ __align__(16) __hip_bfloat16 hmat_lds[2][NSL][300];  // hmat n-slice
  __shared__ __hip_bfloat16 a1c_lds[JP][300];                     // attnh_w[:, :300] cols for our k-slice

  const int wg = blockIdx.x;
  const int tid = threadIdx.x;
  const int gthread = wg * BLK + tid;
  unsigned* ctr = (unsigned*)ws;
  float* W = ws;
  int epoch = 0;

  // ================= K1a: embedding gather + zero exchange/accum buffers =================
  for (int i = gthread; i < 2 * kL * kD; i += NWG * BLK) {
    int side = i / (kL * kD); int r = i % (kL * kD); int t = r / kD; int d = r % kD;
    const int* idx = side ? rinputs : linputs;
    W[(side ? A_REMB : A_LEMB) + r] = emb[(long)idx[t] * kD + d];
  }
  for (int i = gthread; i < 4800; i += NWG * BLK) W[A_HABUF + i] = 0.f;
  for (int i = gthread; i < 19200; i += NWG * BLK) W[A_HPACC + i] = 0.f;  // hpacc + hacc (contiguous)
  gbar(ctr, epoch);

  // ================= K1b: x-projections (xiou = x@ioux_w.T + b; xf = x@fx_w.T + b) =================
  for (int task = wg; task < 64; task += NWG) {
    int side = task & 1; int tb = task >> 1;  // 16-row t-block
    float* xt = (float*)hmp_lds;              // 16*300 f32 staging (hmp not yet live)
    const float* xbase = W + (side ? A_REMB : A_LEMB) + tb * 16 * kD;
    for (int i = tid; i < 16 * kD; i += BLK) xt[i] = xbase[i];
    __syncthreads();
    float* xiou = W + (side ? A_XIOU_R : A_XIOU_L) + tb * 16 * 900;
    float* xf   = W + (side ? A_XF_R   : A_XF_L)   + tb * 16 * 300;
    const float4* xt4 = (const float4*)xt;
    for (int id = tid; id < 1200; id += BLK) {
      int o4 = id >> 2, q = id & 3;           // o-quad x tt-quad register tile
      int o0 = o4 * 4;
      float acc[4][4];
      const float* wrow[4]; float bias[4];
      #pragma unroll
      for (int m = 0; m < 4; ++m) {
        int o = o0 + m;
        if (o < 900) { wrow[m] = ioux_w + o * kD; bias[m] = ioux_b[o]; }
        else         { wrow[m] = fx_w + (o - 900) * kD; bias[m] = fx_b[o - 900]; }
        #pragma unroll
        for (int n = 0; n < 4; ++n) acc[m][n] = bias[m];
      }
      for (int k4 = 0; k4 < 75; ++k4) {
        float4 x4[4];
        #pragma unroll
        for (int n = 0; n < 4; ++n) x4[n] = xt4[(q * 4 + n) * 75 + k4];
        #pragma unroll
        for (int m = 0; m < 4; ++m) {
          float4 w4 = *(const float4*)(wrow[m] + k4 * 4);
          #pragma unroll
          for (int n = 0; n < 4; ++n)
            acc[m][n] += w4.x * x4[n].x + w4.y * x4[n].y + w4.z * x4[n].z + w4.w * x4[n].w;
        }
      }
      #pragma unroll
      for (int m = 0; m < 4; ++m) {
        int o = o0 + m;
        #pragma unroll
        for (int n = 0; n < 4; ++n) {
          int tt = q * 4 + n;
          if (o < 900) xiou[tt * 900 + o] = acc[m][n];
          else         xf[tt * 300 + (o - 900)] = acc[m][n];
        }
      }
    }
    __syncthreads();
  }
  gbar(ctr, epoch);

  // ================= per-thread constants: LSTM weight slice in REGISTERS =================
  // row r = gate*10 + jl; gates 0,1,2 = i,o,u (iouh_w rows gate*300+jg), gate 3 = f (fh_w row jg)
  float wreg[KLEN];
  int r6 = 0, s6 = 0, k0 = 0;
  if (wg < NJW && tid < 240) {
    r6 = tid / NSPLIT; s6 = tid % NSPLIT;
    int gate = r6 / JP, jl = r6 % JP, jg = wg * JP + jl;
    k0 = s6 * KLEN;
    const float* wrow = (gate < 3) ? (iouh_w + (gate * kM + jg) * kM) : (fh_w + jg * kM);
    #pragma unroll
    for (int k = 0; k < KLEN; ++k) wreg[k] = wrow[k0 + k];
  }
  float biasr = 0.f; int ach = 0, ag = 0, ajl = 0, ajg = 0;
  if (wg < NJW && tid < 160) {
    ach = tid / 40; ag = (tid / 10) % 4; ajl = tid % 10; ajg = wg * JP + ajl;
    biasr = (ag < 3) ? iouh_b[ag * kM + ajg] : fh_b[ajg];
  }
  int gch = 0, gjl = 0, gjg = 0;
  if (wg < NJW && tid < 40) { gch = tid / 10; gjl = tid % 10; gjg = wg * JP + gjl; }

  if (tid < 40) c_lds[tid / 10][tid % 10] = 0.f;
  __syncthreads();

  // ================= Stage A: 4 non-attention chains, 512 steps, 1 barrier/step =================
  // ch0: lemb fwd -> hs_lf ; ch1: lemb bwd -> hs_lb ; ch2: remb fwd -> hs_rf ; ch3: remb bwd -> hs_rb
  int p = 0;
  for (int t = 0; t < kL; ++t) {
    for (int i = tid; i < 1200; i += BLK) h_lds[i / 300][i % 300] = W[A_HABUF + p * 1200 + i];
    float xv = 0.f;
    if (wg < NJW && tid < 160) {
      int trow = (ach & 1) ? (511 - t) : t;
      if (ag < 3) xv = W[(ach < 2 ? A_XIOU_L : A_XIOU_R) + trow * 900 + ag * 300 + ajg];
      else        xv = W[(ach < 2 ? A_XF_L   : A_XF_R)   + trow * 300 + ajg];
    }
    __syncthreads();
    if (wg < NJW && tid < 240) {
      #pragma unroll
      for (int ch = 0; ch < 4; ++ch) {
        float acc = 0.f;
        #pragma unroll
        for (int k = 0; k < KLEN; ++k) acc += wreg[k] * h_lds[ch][k0 + k];
        part[ch][r6][s6] = acc;
      }
    }
    __syncthreads();
    if (wg < NJW && tid < 160) {
      float pre = xv + biasr;
      #pragma unroll
      for (int s = 0; s < NSPLIT; ++s) pre += part[ach][ag * 10 + ajl][s];
      gv[ach][ag][ajl] = pre;
    }
    __syncthreads();
    if (wg < NJW && tid < 40) {
      float iv = fsig(gv[gch][0][gjl]);
      float ov = fsig(gv[gch][1][gjl]);
      float uv = ftanh(gv[gch][2][gjl]);
      float fv = fsig(gv[gch][3][gjl]);
      float c = iv * uv + fv * c_lds[gch][gjl];
      c_lds[gch][gjl] = c;
      float h = ov * ftanh(c);
      W[A_HABUF + (p ^ 1) * 1200 + gch * 300 + gjg] = h;
      int hsoff = (gch == 0) ? A_HS_LF : (gch == 1) ? A_HS_LB : (gch == 2) ? A_HS_RF : A_HS_RB;
      W[hsoff + t * 300 + gjg] = h;
    }
    gbar(ctr, epoch);
    p ^= 1;
  }

  // ================= K3a: hs_l = tanh(hs_lf + hs_lb[::-1]) ; hs_r likewise =================
  for (int i = gthread; i < 2 * kL * kM; i += NWG * BLK) {
    int side = i / (kL * kM); int r = i % (kL * kM); int n = r / kM; int j = r % kM;
    float v = ftanh(W[(side ? A_HS_RF : A_HS_LF) + n * kM + j] +
                    W[(side ? A_HS_RB : A_HS_LB) + (511 - n) * kM + j]);
    W[(side ? A_HS_R : A_HS_L) + n * kM + j] = v;
  }
  gbar(ctr, epoch);

  // ================= K3b: attention prep (per-WG LDS residency) =================
  for (int j = tid; j < 300; j += BLK) wa_lds[j] = Wa[j];
  if (wg < NJW)
    for (int i = tid; i < JP * 300; i += BLK) {
      int kl = i / 300, j = i % 300;
      a1c_lds[kl][j] = __float2bfloat16(attnh_w[j * 600 + wg * JP + kl]);
    }
  for (int j = tid; j < 300; j += BLK) {
    float s0 = 0.f, s1 = 0.f;
    for (int n = 0; n < kL; ++n) { s0 += W[A_HS_L + n * 300 + j]; s1 += W[A_HS_R + n * 300 + j]; }
    colsum_lds[0][j] = s0; colsum_lds[1][j] = s1;
  }
  // hm_proj[n][j] = hs[n] . attnh_w[j, 300:600] + attnh_b[j], for our n-slice (bf16 in LDS)
  for (int side = 0; side < 2; ++side) {
    __syncthreads();
    float* stage = (float*)hmat_lds;  // f32 staging of 16 hs rows (hmat not yet live)
    for (int i = tid; i < NSL * 300; i += BLK)
      stage[i] = W[(side ? A_HS_R : A_HS_L) + (wg * NSL) * 300 + i];
    __syncthreads();
    const float4* st4 = (const float4*)stage;
    for (int id = tid; id < 1200; id += BLK) {
      int j = id >> 2, q = id & 3;
      float b = attnh_b[j];
      float acc[4] = {b, b, b, b};
      const float* wrow = attnh_w + j * 600 + 300;
      for (int k4 = 0; k4 < 75; ++k4) {
        float4 w4 = *(const float4*)(wrow + k4 * 4);
        #pragma unroll
        for (int m = 0; m < 4; ++m) {
          float4 x4 = st4[(q * 4 + m) * 75 + k4];
          acc[m] += w4.x * x4.x + w4.y * x4.y + w4.z * x4.z + w4.w * x4.w;
        }
      }
      #pragma unroll
      for (int m = 0; m < 4; ++m) hmp_lds[side][q * 4 + m][j] = __float2bfloat16(acc[m]);
    }
  }
  __syncthreads();
  for (int i = tid; i < 2 * NSL * 300; i += BLK) {
    int side = i / (NSL * 300); int r = i % (NSL * 300);
    hmat_lds[side][r / 300][r % 300] =
        __float2bfloat16(W[(side ? A_HS_R : A_HS_L) + (wg * NSL) * 300 + r]);
  }
  for (int i = tid; i < 1216; i += BLK) ((float*)h_lds)[i] = 0.f;
  if (tid < 40) c_lds[tid / 10][tid % 10] = 0.f;
  gbar(ctr, epoch);

  // ================= Stage B: attention chains, 2 barriers/step =================
  // ch0: (remb fwd, hmat=hs_l) full ; ch1: (lemb fwd, hmat=hs_r) full
  // ch2: (rflip, hs_l) step0 only -> rh_b1 ; ch3: (lflip, hs_r) step0 only -> lh_b2
  int pb = 0;
  for (int t = 0; t < kL; ++t) {
    const int nact = (t == 0) ? 4 : 2;
    // ---- Phase D: LSTM slice + hproj k-partials ----
    float xvb = 0.f;
    if (wg < NJW && tid < 160 && ach < nact) {
      int trow = (ach < 2) ? t : 511;
      int useL = ach & 1;  // ch0,2 -> remb(x_r); ch1,3 -> lemb(x_l)
      if (ag < 3) xvb = W[(useL ? A_XIOU_L : A_XIOU_R) + trow * 900 + ag * 300 + ajg];
      else        xvb = W[(useL ? A_XF_L   : A_XF_R)   + trow * 300 + ajg];
    }
    __syncthreads();
    if (wg < NJW && tid < 240) {
      for (int ch = 0; ch < nact; ++ch) {
        float acc = 0.f;
        #pragma unroll
        for (int k = 0; k < KLEN; ++k) acc += wreg[k] * h_lds[ch][k0 + k];
        part[ch][r6][s6] = acc;
      }
    }
    __syncthreads();
    if (wg < NJW && tid < 160 && ach < nact) {
      float pre = xvb + biasr;
      #pragma unroll
      for (int s = 0; s < NSPLIT; ++s) pre += part[ach][ag * 10 + ajl][s];
      gv[ach][ag][ajl] = pre;
    }
    __syncthreads();
    if (wg < NJW && tid < 40 && gch < nact) {
      float iv = fsig(gv[gch][0][gjl]);
      float ov = fsig(gv[gch][1][gjl]);
      float uv = ftanh(gv[gch][2][gjl]);
      float fv = fsig(gv[gch][3][gjl]);
      float c = iv * uv + fv * c_lds[gch][gjl];
      c_lds[gch][gjl] = c;
      float h = ov * ftanh(c);
      W[A_HBBUF + pb * 1200 + gch * 300 + gjg] = h;
      hnew_lds[gch][gjl] = h;
    }
    __syncthreads();
    if (wg < NJW) {
      for (int ch = 0; ch < nact; ++ch)
        for (int j = tid; j < 300; j += BLK) {
          float acc = 0.f;
          #pragma unroll
          for (int kl = 0; kl < JP; ++kl)
            acc += hnew_lds[ch][kl] * __bfloat162float(a1c_lds[kl][j]);
          atomicAdd(&W[A_HPACC + ((pb * SEG + (wg & 3)) * 4 + ch) * 300 + j], acc);
        }
    }
    gbar(ctr, epoch);  // B1

    // ---- Phase P2: scores (n-slice) + softmax-denominator + PV numerator atomics ----
    for (int i = tid; i < SEG * 4 * 300; i += BLK) W[A_HACC + (pb ^ 1) * 4800 + i] = 0.f;
    for (int i = tid; i < nact * 300; i += BLK) {
      int ch = i / 300, j = i % 300;
      float s_ = 0.f;
      #pragma unroll
      for (int sg = 0; sg < SEG; ++sg) s_ += W[A_HPACC + ((pb * SEG + sg) * 4 + ch) * 300 + j];
      hpj_lds[ch][j] = s_;
    }
    __syncthreads();
    float* pf = &part[0][0][0];
    for (int id = tid; id < nact * NSL * 8; id += BLK) {
      int ch = id / 128; int rem = id % 128; int nl = rem / 8; int js = rem % 8;
      int side = ch & 1;
      int j0 = js * 38; int j1 = j0 + 38; if (j1 > 300) j1 = 300;
      float acc = 0.f;
      for (int j = j0; j < j1; ++j)
        acc += wa_lds[j] * ftanh(hpj_lds[ch][j] + __bfloat162float(hmp_lds[side][nl][j]));
      pf[id] = acc;
    }
    __syncthreads();
    if (tid < nact * NSL) {
      int ch = tid / NSL, nl = tid % NSL;
      float sc = 0.f;
      #pragma unroll
      for (int js = 0; js < 8; ++js) sc += pf[(ch * NSL + nl) * 8 + js];
      sc = fminf(fmaxf(sc, -60.f), 60.f);
      sc_lds[ch][nl] = __expf(sc);  // no max-shift: |score| <= sum|Wa| ~ 12, safe in f32
    }
    __syncthreads();
    if (tid < nact) {
      float dsum = 0.f;
      #pragma unroll
      for (int nl = 0; nl < NSL; ++nl) dsum += sc_lds[tid][nl];
      W[A_DACC + (pb * 32 + wg) * 4 + tid] = dsum;
    }
    for (int ch = 0; ch < nact; ++ch) {
      int side = ch & 1;
      for (int j = tid; j < 300; j += BLK) {
        float acc = 0.f;
        #pragma unroll
        for (int nl = 0; nl < NSL; ++nl)
          acc += sc_lds[ch][nl] * __bfloat162float(hmat_lds[side][nl][j]);
        atomicAdd(&W[A_HACC + ((pb * SEG + (wg & 3)) * 4 + ch) * 300 + j], acc);
      }
    }
    gbar(ctr, epoch);  // B2

    // ---- Phase A: assemble h_att = h_lstm + colsum - (s @ hmat) into local LDS ----
    for (int i = tid; i < SEG * 4 * 300; i += BLK) W[A_HPACC + pb * 4800 + i] = 0.f;
    if (tid < nact) {
      float den = 0.f;
      #pragma unroll
      for (int w2 = 0; w2 < NWG; ++w2) den += W[A_DACC + (pb * 32 + w2) * 4 + tid];
      gv[0][0][tid] = den;
    }
    __syncthreads();
    for (int ch = 0; ch < nact; ++ch) {
      float inv = 1.f / gv[0][0][ch];
      int side = ch & 1;
      for (int j = tid; j < 300; j += BLK) {
        float s_ = 0.f;
        #pragma unroll
        for (int sg = 0; sg < SEG; ++sg) s_ += W[A_HACC + ((pb * SEG + sg) * 4 + ch) * 300 + j];
        float val = W[A_HBBUF + pb * 1200 + ch * 300 + j] + colsum_lds[side][j] - s_ * inv;
        h_lds[ch][j] = val;
        if (t == 511 && ch == 0) W[A_BFIN + 0   + j] = val;  // rh_f1
        if (t == 511 && ch == 1) W[A_BFIN + 600 + j] = val;  // lh_f2
        if (t == 0   && ch == 2) W[A_BFIN + 300 + j] = val;  // rh_b1
        if (t == 0   && ch == 3) W[A_BFIN + 900 + j] = val;  // lh_b2
      }
    }
    __syncthreads();
    pb ^= 1;
  }
  gbar(ctr, epoch);

  // ================= K5: final head (WG0 only) =================
  if (wg == 0) {
    float* hl = (float*)h_lds;    // lhid [0,600), rhid [608,1208)
    float* vec = (float*)hpj_lds; // [0,1200)
    float* hid = &part[0][0][0];  // [0,200)
    for (int j = tid; j < 300; j += BLK) {
      float lf = W[A_HS_LF + 511 * 300 + j] + W[A_BFIN + 600 + j];
      float lb = W[A_HS_LB + j]             + W[A_BFIN + 900 + j];
      float rf = W[A_BFIN + j]              + W[A_HS_RF + 511 * 300 + j];
      float rb = W[A_BFIN + 300 + j]        + W[A_HS_RB + j];
      hl[j]        = ftanh(lf);
      hl[300 + j]  = ftanh(lb);
      hl[608 + j]  = ftanh(rf);
      hl[908 + j]  = ftanh(rb);
    }
    __syncthreads();
    for (int i = tid; i < 600; i += BLK) {
      float a = hl[i], b = hl[608 + i];
      vec[i] = a * b; vec[600 + i] = fabsf(a - b);
    }
    __syncthreads();
    for (int hh = tid; hh < 200; hh += BLK) {
      float acc = wh_b[hh];
      const float* wr = wh_w + hh * 1200;
      for (int i2 = 0; i2 < 1200; ++i2) acc += wr[i2] * vec[i2];
      hid[hh] = fsig(acc);
    }
    __syncthreads();
    if (tid < 5) {
      float acc = wp_b[tid];
      const float* wr = wp_w + tid * 200;
      for (int h2 = 0; h2 < 200; ++h2) acc += wr[h2] * hid[h2];
      red_lds[tid] = acc;
    }
    __syncthreads();
    if (tid == 0) {
      float mx = red_lds[0];
      for (int c2 = 1; c2 < 5; ++c2) mx = fmaxf(mx, red_lds[c2]);
      float se = 0.f;
      for (int c2 = 0; c2 < 5; ++c2) se += __expf(red_lds[c2] - mx);
      float lse = logf(se) + mx;
      for (int c2 = 0; c2 < 5; ++c2) out[c2] = red_lds[c2] - lse;
    }
  }
}

extern "C" void kernel_launch(void* const* d_in, const int* in_sizes, int n_in,
                              void* d_out, int out_size, void* d_ws, size_t ws_size,
                              hipStream_t stream) {
  (void)in_sizes; (void)n_in; (void)out_size; (void)ws_size;
  // zero the device-barrier counter region (ws is re-poisoned to 0xAA before every launch)
  hipMemsetAsync(d_ws, 0, 256, stream);
  treelstm_kernel<<<NWG, BLK, 0, stream>>>(
      (const int*)d_in[0], (const int*)d_in[1], (const float*)d_in[2],
      (const float*)d_in[3], (const float*)d_in[4], (const float*)d_in[5],
      (const float*)d_in[6], (const float*)d_in[7], (const float*)d_in[8],
      (const float*)d_in[9], (const float*)d_in[10], (const float*)d_in[11],
      (const float*)d_in[12], (const float*)d_in[13], (const float*)d_in[14],
      (const float*)d_in[15], (const float*)d_in[16], (const float*)d_in[17],
      (float*)d_ws, (float*)d_out);
}

// Round 3
// 10099.542 us; speedup vs baseline: 1.0849x; 1.0849x over previous
//
#include <hip/hip_runtime.h>
#include <hip/hip_bf16.h>

// ---------------- problem constants ----------------
constexpr int kL = 512;    // sequence length
constexpr int kD = 300;    // embedding dim
constexpr int kM = 300;    // hidden dim
constexpr int NWG = 32;    // workgroups (all co-resident; device barrier group)
constexpr int BLK = 256;   // threads per WG
constexpr int JP = 10;     // h-indices owned per WG (j-slice)
constexpr int NJW = 30;    // WGs that own a j-slice (30*10 = 300)
constexpr int NSPLIT = 6;  // k-splits per gate-row dot
constexpr int KLEN = 50;   // 300 / 6
constexpr int NSL = 16;    // n-slice per WG (32*16 = 512)
constexpr int SEG = 4;     // atomic-accum segmentation (contention reduction)

// ---------------- workspace layout (float offsets; [0] holds the barrier counter) ----------------
constexpr int A_LEMB   = 1024;
constexpr int A_REMB   = A_LEMB   + kL*kD;      // gathered embeddings
constexpr int A_XIOU_L = A_REMB   + kL*kD;      // x@ioux_w.T + ioux_b   [512][900]
constexpr int A_XF_L   = A_XIOU_L + kL*900;     // x@fx_w.T + fx_b       [512][300]
constexpr int A_XIOU_R = A_XF_L   + kL*300;
constexpr int A_XF_R   = A_XIOU_R + kL*900;
constexpr int A_HS_LF  = A_XF_R   + kL*300;     // stage A hidden traces
constexpr int A_HS_LB  = A_HS_LF  + kL*300;
constexpr int A_HS_RF  = A_HS_LB  + kL*300;
constexpr int A_HS_RB  = A_HS_RF  + kL*300;
constexpr int A_HS_L   = A_HS_RB  + kL*300;     // tanh(hs_l_f + hs_l_b[::-1])  (= hmat_l)
constexpr int A_HS_R   = A_HS_L   + kL*300;
constexpr int A_HABUF  = A_HS_R   + kL*300;     // stage A h exchange [2][4][300]
constexpr int A_HBBUF  = A_HABUF  + 2400;       // stage B h_lstm exchange [2][4][300]
constexpr int A_HPACC  = A_HBBUF  + 2400;       // hproj atomic accum [2][SEG][4][300]
constexpr int A_HACC   = A_HPACC  + 9600;       // PV numerator atomic accum [2][SEG][4][300]
constexpr int A_DACC   = A_HACC   + 9600;       // softmax denom slots [2][32][4]
constexpr int A_BFIN   = A_DACC   + 256;        // stage B finals: rh_f1, rh_b1, lh_f2, lh_b2
constexpr int A_END    = A_BFIN   + 1200;       // ~9.94 MB of ws

__device__ __forceinline__ float fsig(float x) { return 1.0f / (1.0f + __expf(-x)); }
__device__ __forceinline__ float ftanh(float x) {
  x = fminf(fmaxf(x, -15.f), 15.f);
  float e = __expf(2.f * x);
  return (e - 1.f) / (e + 1.f);
}

// Agent-scope (device-coherent, L3/coherence-point) accesses for the small
// loop-crossing buffers. These bypass the stale-L2 problem per-access, so the
// per-step barrier needs NO cache-wide fence.
__device__ __forceinline__ float aload(const float* p) {
  return __hip_atomic_load(p, __ATOMIC_RELAXED, __HIP_MEMORY_SCOPE_AGENT);
}
__device__ __forceinline__ void astore(float* p, float v) {
  __hip_atomic_store(p, v, __ATOMIC_RELAXED, __HIP_MEMORY_SCOPE_AGENT);
}

// Heavy barrier (full fence) — prologue-only.
__device__ __forceinline__ void gbar(unsigned* ctr, int& epoch) {
  __syncthreads();
  if (threadIdx.x == 0) {
    ++epoch;
    __threadfence();
    atomicAdd(ctr, 1u);
    const unsigned tgt = (unsigned)(NWG * epoch);
    while (__hip_atomic_load(ctr, __ATOMIC_RELAXED, __HIP_MEMORY_SCOPE_AGENT) < tgt)
      __builtin_amdgcn_s_sleep(1);
    __threadfence();
  }
  __syncthreads();
}

// Fast barrier: __syncthreads drains each wave's outstanding sc1 stores
// (vmcnt) before tid0's arrive-add, so the add is a release for them; readers
// use sc1 loads which fetch from the coherence point, so no invalidate needed.
__device__ __forceinline__ void gbar_fast(unsigned* ctr, int& epoch) {
  __syncthreads();
  if (threadIdx.x == 0) {
    ++epoch;
    atomicAdd(ctr, 1u);
    const unsigned tgt = (unsigned)(NWG * epoch);
    while (__hip_atomic_load(ctr, __ATOMIC_RELAXED, __HIP_MEMORY_SCOPE_AGENT) < tgt)
      __builtin_amdgcn_s_sleep(1);
  }
  __syncthreads();
}

__global__ __launch_bounds__(BLK) void treelstm_kernel(
    const int* __restrict__ linputs, const int* __restrict__ rinputs,
    const float* __restrict__ emb,
    const float* __restrict__ ioux_w, const float* __restrict__ ioux_b,
    const float* __restrict__ iouh_w, const float* __restrict__ iouh_b,
    const float* __restrict__ fx_w,  const float* __restrict__ fx_b,
    const float* __restrict__ fh_w,  const float* __restrict__ fh_b,
    const float* __restrict__ Wa,    const float* __restrict__ attnh_w,
    const float* __restrict__ attnh_b,
    const float* __restrict__ wh_w,  const float* __restrict__ wh_b,
    const float* __restrict__ wp_w,  const float* __restrict__ wp_b,
    float* __restrict__ ws, float* __restrict__ out) {

  __shared__ __align__(16) float h_lds[4][304];
  __shared__ __align__(16) float hpj_lds[4][304];
  __shared__ __align__(16) float part[4][40][6];
  __shared__ float gv[4][4][10];
  __shared__ float c_lds[4][10];
  __shared__ float hnew_lds[4][10];
  __shared__ float dred[4][32];
  __shared__ __align__(16) float colsum_lds[2][300];
  __shared__ float wa_lds[300];
  __shared__ float sc_lds[4][16];
  __shared__ float red_lds[32];
  __shared__ __align__(16) __hip_bfloat16 hmp_lds[2][NSL][300];   // hm_proj n-slice
  __shared__ __align__(16) __hip_bfloat16 hmat_lds[2][NSL][300];  // hmat n-slice
  __shared__ __hip_bfloat16 a1c_lds[JP][300];                     // attnh_w[:, :300] cols for our k-slice

  const int wg = blockIdx.x;
  const int tid = threadIdx.x;
  const int gthread = wg * BLK + tid;
  unsigned* ctr = (unsigned*)ws;
  float* W = ws;
  int epoch = 0;

  // ================= K1a: embedding gather + zero exchange/accum buffers =================
  for (int i = gthread; i < 2 * kL * kD; i += NWG * BLK) {
    int side = i / (kL * kD); int r = i % (kL * kD); int t = r / kD; int d = r % kD;
    const int* idx = side ? rinputs : linputs;
    W[(side ? A_REMB : A_LEMB) + r] = emb[(long)idx[t] * kD + d];
  }
  // exchange/accum regions are ONLY ever touched with agent-scope ops
  for (int i = gthread; i < 4800; i += NWG * BLK) astore(&W[A_HABUF + i], 0.f);
  for (int i = gthread; i < 19200; i += NWG * BLK) astore(&W[A_HPACC + i], 0.f);
  gbar(ctr, epoch);  // heavy: emb gather was normal stores

  // ================= K1b: x-projections (xiou = x@ioux_w.T + b; xf = x@fx_w.T + b) =================
  for (int task = wg; task < 64; task += NWG) {
    int side = task & 1; int tb = task >> 1;  // 16-row t-block
    float* xt = (float*)hmp_lds;              // 16*300 f32 staging (hmp not yet live)
    const float* xbase = W + (side ? A_REMB : A_LEMB) + tb * 16 * kD;
    for (int i = tid; i < 16 * kD; i += BLK) xt[i] = xbase[i];
    __syncthreads();
    float* xiou = W + (side ? A_XIOU_R : A_XIOU_L) + tb * 16 * 900;
    float* xf   = W + (side ? A_XF_R   : A_XF_L)   + tb * 16 * 300;
    const float4* xt4 = (const float4*)xt;
    for (int id = tid; id < 1200; id += BLK) {
      int o4 = id >> 2, q = id & 3;           // o-quad x tt-quad register tile
      int o0 = o4 * 4;
      float acc[4][4];
      const float* wrow[4]; float bias[4];
      #pragma unroll
      for (int m = 0; m < 4; ++m) {
        int o = o0 + m;
        if (o < 900) { wrow[m] = ioux_w + o * kD; bias[m] = ioux_b[o]; }
        else         { wrow[m] = fx_w + (o - 900) * kD; bias[m] = fx_b[o - 900]; }
        #pragma unroll
        for (int n = 0; n < 4; ++n) acc[m][n] = bias[m];
      }
      for (int k4 = 0; k4 < 75; ++k4) {
        float4 x4[4];
        #pragma unroll
        for (int n = 0; n < 4; ++n) x4[n] = xt4[(q * 4 + n) * 75 + k4];
        #pragma unroll
        for (int m = 0; m < 4; ++m) {
          float4 w4 = *(const float4*)(wrow[m] + k4 * 4);
          #pragma unroll
          for (int n = 0; n < 4; ++n)
            acc[m][n] += w4.x * x4[n].x + w4.y * x4[n].y + w4.z * x4[n].z + w4.w * x4[n].w;
        }
      }
      #pragma unroll
      for (int m = 0; m < 4; ++m) {
        int o = o0 + m;
        #pragma unroll
        for (int n = 0; n < 4; ++n) {
          int tt = q * 4 + n;
          if (o < 900) xiou[tt * 900 + o] = acc[m][n];
          else         xf[tt * 300 + (o - 900)] = acc[m][n];
        }
      }
    }
    __syncthreads();
  }
  gbar(ctr, epoch);  // heavy: xiou/xf were normal stores; read-only (L2-cacheable) afterwards

  // ================= per-thread constants: LSTM weight slice in REGISTERS =================
  // row r = gate*10 + jl; gates 0,1,2 = i,o,u (iouh_w rows gate*300+jg), gate 3 = f (fh_w row jg)
  float wreg[KLEN];
  int r6 = 0, s6 = 0, k0 = 0;
  if (wg < NJW && tid < 240) {
    r6 = tid / NSPLIT; s6 = tid % NSPLIT;
    int gate = r6 / JP, jl = r6 % JP, jg = wg * JP + jl;
    k0 = s6 * KLEN;
    const float* wrow = (gate < 3) ? (iouh_w + (gate * kM + jg) * kM) : (fh_w + jg * kM);
    #pragma unroll
    for (int k = 0; k < KLEN; ++k) wreg[k] = wrow[k0 + k];
  }
  float biasr = 0.f; int ach = 0, ag = 0, ajl = 0, ajg = 0;
  if (wg < NJW && tid < 160) {
    ach = tid / 40; ag = (tid / 10) % 4; ajl = tid % 10; ajg = wg * JP + ajl;
    biasr = (ag < 3) ? iouh_b[ag * kM + ajg] : fh_b[ajg];
  }
  int gch = 0, gjl = 0, gjg = 0;
  if (wg < NJW && tid < 40) { gch = tid / 10; gjl = tid % 10; gjg = wg * JP + gjl; }

  if (tid < 40) c_lds[tid / 10][tid % 10] = 0.f;
  __syncthreads();

  // ================= Stage A: 4 non-attention chains, 512 steps, 1 fast barrier/step =================
  // ch0: lemb fwd -> hs_lf ; ch1: lemb bwd -> hs_lb ; ch2: remb fwd -> hs_rf ; ch3: remb bwd -> hs_rb
  int p = 0;
  for (int t = 0; t < kL; ++t) {
    for (int i = tid; i < 1200; i += BLK)
      h_lds[i / 300][i % 300] = aload(&W[A_HABUF + p * 1200 + i]);
    float xv = 0.f;
    if (wg < NJW && tid < 160) {
      int trow = (ach & 1) ? (511 - t) : t;
      if (ag < 3) xv = W[(ach < 2 ? A_XIOU_L : A_XIOU_R) + trow * 900 + ag * 300 + ajg];
      else        xv = W[(ach < 2 ? A_XF_L   : A_XF_R)   + trow * 300 + ajg];
    }
    __syncthreads();
    if (wg < NJW && tid < 240) {
      #pragma unroll
      for (int ch = 0; ch < 4; ++ch) {
        float acc = 0.f;
        #pragma unroll
        for (int k = 0; k < KLEN; ++k) acc += wreg[k] * h_lds[ch][k0 + k];
        part[ch][r6][s6] = acc;
      }
    }
    __syncthreads();
    if (wg < NJW && tid < 160) {
      float pre = xv + biasr;
      #pragma unroll
      for (int s = 0; s < NSPLIT; ++s) pre += part[ach][ag * 10 + ajl][s];
      gv[ach][ag][ajl] = pre;
    }
    __syncthreads();
    if (wg < NJW && tid < 40) {
      float iv = fsig(gv[gch][0][gjl]);
      float ov = fsig(gv[gch][1][gjl]);
      float uv = ftanh(gv[gch][2][gjl]);
      float fv = fsig(gv[gch][3][gjl]);
      float c = iv * uv + fv * c_lds[gch][gjl];
      c_lds[gch][gjl] = c;
      float h = ov * ftanh(c);
      astore(&W[A_HABUF + (p ^ 1) * 1200 + gch * 300 + gjg], h);
      int hsoff = (gch == 0) ? A_HS_LF : (gch == 1) ? A_HS_LB : (gch == 2) ? A_HS_RF : A_HS_RB;
      astore(&W[hsoff + t * 300 + gjg], h);  // write-through: later normal reads are fresh
    }
    gbar_fast(ctr, epoch);
    p ^= 1;
  }

  // ================= K3a: hs_l = tanh(hs_lf + hs_lb[::-1]) ; hs_r likewise =================
  // hs traces were astore-written (never L2-cached pre-write) -> normal reads are coherent.
  for (int i = gthread; i < 2 * kL * kM; i += NWG * BLK) {
    int side = i / (kL * kM); int r = i % (kL * kM); int n = r / kM; int j = r % kM;
    float v = ftanh(W[(side ? A_HS_RF : A_HS_LF) + n * kM + j] +
                    W[(side ? A_HS_RB : A_HS_LB) + (511 - n) * kM + j]);
    astore(&W[(side ? A_HS_R : A_HS_L) + n * kM + j], v);
  }
  gbar_fast(ctr, epoch);

  // ================= K3b: attention prep (per-WG LDS residency) =================
  for (int j = tid; j < 300; j += BLK) wa_lds[j] = Wa[j];
  if (wg < NJW)
    for (int i = tid; i < JP * 300; i += BLK) {
      int kl = i / 300, j = i % 300;
      a1c_lds[kl][j] = __float2bfloat16(attnh_w[j * 600 + wg * JP + kl]);
    }
  for (int j = tid; j < 300; j += BLK) {
    float s0 = 0.f, s1 = 0.f;
    for (int n = 0; n < kL; ++n) { s0 += W[A_HS_L + n * 300 + j]; s1 += W[A_HS_R + n * 300 + j]; }
    colsum_lds[0][j] = s0; colsum_lds[1][j] = s1;
  }
  // hm_proj[n][j] = hs[n] . attnh_w[j, 300:600] + attnh_b[j], for our n-slice (bf16 in LDS)
  for (int side = 0; side < 2; ++side) {
    __syncthreads();
    float* stage = (float*)hmat_lds;  // f32 staging of 16 hs rows (hmat not yet live)
    for (int i = tid; i < NSL * 300; i += BLK)
      stage[i] = W[(side ? A_HS_R : A_HS_L) + (wg * NSL) * 300 + i];
    __syncthreads();
    const float4* st4 = (const float4*)stage;
    for (int id = tid; id < 1200; id += BLK) {
      int j = id >> 2, q = id & 3;
      float b = attnh_b[j];
      float acc[4] = {b, b, b, b};
      const float* wrow = attnh_w + j * 600 + 300;
      for (int k4 = 0; k4 < 75; ++k4) {
        float4 w4 = *(const float4*)(wrow + k4 * 4);
        #pragma unroll
        for (int m = 0; m < 4; ++m) {
          float4 x4 = st4[(q * 4 + m) * 75 + k4];
          acc[m] += w4.x * x4.x + w4.y * x4.y + w4.z * x4.z + w4.w * x4.w;
        }
      }
      #pragma unroll
      for (int m = 0; m < 4; ++m) hmp_lds[side][q * 4 + m][j] = __float2bfloat16(acc[m]);
    }
  }
  __syncthreads();
  for (int i = tid; i < 2 * NSL * 300; i += BLK) {
    int side = i / (NSL * 300); int r = i % (NSL * 300);
    hmat_lds[side][r / 300][r % 300] =
        __float2bfloat16(W[(side ? A_HS_R : A_HS_L) + (wg * NSL) * 300 + r]);
  }
  for (int i = tid; i < 1216; i += BLK) ((float*)h_lds)[i] = 0.f;
  if (tid < 40) c_lds[tid / 10][tid % 10] = 0.f;
  gbar_fast(ctr, epoch);

  // ================= Stage B: attention chains, 2 fast barriers/step =================
  // ch0: (remb fwd, hmat=hs_l) full ; ch1: (lemb fwd, hmat=hs_r) full
  // ch2: (rflip, hs_l) step0 only -> rh_b1 ; ch3: (lflip, hs_r) step0 only -> lh_b2
  int pb = 0;
  for (int t = 0; t < kL; ++t) {
    const int nact = (t == 0) ? 4 : 2;
    // ---- Phase D: LSTM slice + hproj k-partials ----
    float xvb = 0.f;
    if (wg < NJW && tid < 160 && ach < nact) {
      int trow = (ach < 2) ? t : 511;
      int useL = ach & 1;  // ch0,2 -> remb(x_r); ch1,3 -> lemb(x_l)
      if (ag < 3) xvb = W[(useL ? A_XIOU_L : A_XIOU_R) + trow * 900 + ag * 300 + ajg];
      else        xvb = W[(useL ? A_XF_L   : A_XF_R)   + trow * 300 + ajg];
    }
    __syncthreads();
    if (wg < NJW && tid < 240) {
      for (int ch = 0; ch < nact; ++ch) {
        float acc = 0.f;
        #pragma unroll
        for (int k = 0; k < KLEN; ++k) acc += wreg[k] * h_lds[ch][k0 + k];
        part[ch][r6][s6] = acc;
      }
    }
    __syncthreads();
    if (wg < NJW && tid < 160 && ach < nact) {
      float pre = xvb + biasr;
      #pragma unroll
      for (int s = 0; s < NSPLIT; ++s) pre += part[ach][ag * 10 + ajl][s];
      gv[ach][ag][ajl] = pre;
    }
    __syncthreads();
    if (wg < NJW && tid < 40 && gch < nact) {
      float iv = fsig(gv[gch][0][gjl]);
      float ov = fsig(gv[gch][1][gjl]);
      float uv = ftanh(gv[gch][2][gjl]);
      float fv = fsig(gv[gch][3][gjl]);
      float c = iv * uv + fv * c_lds[gch][gjl];
      c_lds[gch][gjl] = c;
      float h = ov * ftanh(c);
      astore(&W[A_HBBUF + pb * 1200 + gch * 300 + gjg], h);
      hnew_lds[gch][gjl] = h;
    }
    __syncthreads();
    if (wg < NJW) {
      for (int ch = 0; ch < nact; ++ch)
        for (int j = tid; j < 300; j += BLK) {
          float acc = 0.f;
          #pragma unroll
          for (int kl = 0; kl < JP; ++kl)
            acc += hnew_lds[ch][kl] * __bfloat162float(a1c_lds[kl][j]);
          atomicAdd(&W[A_HPACC + ((pb * SEG + (wg & 3)) * 4 + ch) * 300 + j], acc);
        }
    }
    gbar_fast(ctr, epoch);  // B1

    // ---- Phase P2: scores (n-slice) + softmax-denominator + PV numerator atomics ----
    for (int i = tid; i < SEG * 4 * 300; i += BLK) astore(&W[A_HACC + (pb ^ 1) * 4800 + i], 0.f);
    for (int i = tid; i < nact * 300; i += BLK) {
      int ch = i / 300, j = i % 300;
      float s_ = 0.f;
      #pragma unroll
      for (int sg = 0; sg < SEG; ++sg) s_ += aload(&W[A_HPACC + ((pb * SEG + sg) * 4 + ch) * 300 + j]);
      hpj_lds[ch][j] = s_;
    }
    __syncthreads();
    float* pf = &part[0][0][0];
    for (int id = tid; id < nact * NSL * 8; id += BLK) {
      int ch = id / 128; int rem = id % 128; int nl = rem / 8; int js = rem % 8;
      int side = ch & 1;
      int j0 = js * 38; int j1 = j0 + 38; if (j1 > 300) j1 = 300;
      float acc = 0.f;
      for (int j = j0; j < j1; ++j)
        acc += wa_lds[j] * ftanh(hpj_lds[ch][j] + __bfloat162float(hmp_lds[side][nl][j]));
      pf[id] = acc;
    }
    __syncthreads();
    if (tid < nact * NSL) {
      int ch = tid / NSL, nl = tid % NSL;
      float sc = 0.f;
      #pragma unroll
      for (int js = 0; js < 8; ++js) sc += pf[(ch * NSL + nl) * 8 + js];
      sc = fminf(fmaxf(sc, -60.f), 60.f);
      sc_lds[ch][nl] = __expf(sc);  // no max-shift: |score| <= sum|Wa| ~ 12, safe in f32
    }
    __syncthreads();
    if (tid < nact) {
      float dsum = 0.f;
      #pragma unroll
      for (int nl = 0; nl < NSL; ++nl) dsum += sc_lds[tid][nl];
      astore(&W[A_DACC + (pb * 32 + wg) * 4 + tid], dsum);
    }
    for (int ch = 0; ch < nact; ++ch) {
      int side = ch & 1;
      for (int j = tid; j < 300; j += BLK) {
        float acc = 0.f;
        #pragma unroll
        for (int nl = 0; nl < NSL; ++nl)
          acc += sc_lds[ch][nl] * __bfloat162float(hmat_lds[side][nl][j]);
        atomicAdd(&W[A_HACC + ((pb * SEG + (wg & 3)) * 4 + ch) * 300 + j], acc);
      }
    }
    gbar_fast(ctr, epoch);  // B2

    // ---- Phase A: assemble h_att = h_lstm + colsum - (s @ hmat) into local LDS ----
    for (int i = tid; i < SEG * 4 * 300; i += BLK) astore(&W[A_HPACC + pb * 4800 + i], 0.f);
    if (tid < 32 * nact) {  // parallel fetch of per-WG denominator slots
      int ch = tid >> 5, w2 = tid & 31;
      dred[ch][w2] = aload(&W[A_DACC + (pb * 32 + w2) * 4 + ch]);
    }
    __syncthreads();
    if (tid < nact) {
      float den = 0.f;
      #pragma unroll
      for (int w2 = 0; w2 < NWG; ++w2) den += dred[tid][w2];
      gv[0][0][tid] = den;
    }
    __syncthreads();
    for (int ch = 0; ch < nact; ++ch) {
      float inv = 1.f / gv[0][0][ch];
      int side = ch & 1;
      for (int j = tid; j < 300; j += BLK) {
        float s_ = 0.f;
        #pragma unroll
        for (int sg = 0; sg < SEG; ++sg) s_ += aload(&W[A_HACC + ((pb * SEG + sg) * 4 + ch) * 300 + j]);
        float val = aload(&W[A_HBBUF + pb * 1200 + ch * 300 + j]) + colsum_lds[side][j] - s_ * inv;
        h_lds[ch][j] = val;
        if (t == 511 && ch == 0) astore(&W[A_BFIN + 0   + j], val);  // rh_f1
        if (t == 511 && ch == 1) astore(&W[A_BFIN + 600 + j], val);  // lh_f2
        if (t == 0   && ch == 2) astore(&W[A_BFIN + 300 + j], val);  // rh_b1
        if (t == 0   && ch == 3) astore(&W[A_BFIN + 900 + j], val);  // lh_b2
      }
    }
    __syncthreads();
    pb ^= 1;
  }
  gbar_fast(ctr, epoch);

  // ================= K5: final head (WG0 only) =================
  if (wg == 0) {
    float* hl = (float*)h_lds;    // lhid [0,600), rhid [608,1208)
    float* vec = (float*)hpj_lds; // [0,1200)
    float* hid = &part[0][0][0];  // [0,200)
    for (int j = tid; j < 300; j += BLK) {
      float lf = W[A_HS_LF + 511 * 300 + j] + aload(&W[A_BFIN + 600 + j]);
      float lb = W[A_HS_LB + j]             + aload(&W[A_BFIN + 900 + j]);
      float rf = aload(&W[A_BFIN + j])      + W[A_HS_RF + 511 * 300 + j];
      float rb = aload(&W[A_BFIN + 300 + j]) + W[A_HS_RB + j];
      hl[j]        = ftanh(lf);
      hl[300 + j]  = ftanh(lb);
      hl[608 + j]  = ftanh(rf);
      hl[908 + j]  = ftanh(rb);
    }
    __syncthreads();
    for (int i = tid; i < 600; i += BLK) {
      float a = hl[i], b = hl[608 + i];
      vec[i] = a * b; vec[600 + i] = fabsf(a - b);
    }
    __syncthreads();
    for (int hh = tid; hh < 200; hh += BLK) {
      float acc = wh_b[hh];
      const float* wr = wh_w + hh * 1200;
      for (int i2 = 0; i2 < 1200; ++i2) acc += wr[i2] * vec[i2];
      hid[hh] = fsig(acc);
    }
    __syncthreads();
    if (tid < 5) {
      float acc = wp_b[tid];
      const float* wr = wp_w + tid * 200;
      for (int h2 = 0; h2 < 200; ++h2) acc += wr[h2] * hid[h2];
      red_lds[tid] = acc;
    }
    __syncthreads();
    if (tid == 0) {
      float mx = red_lds[0];
      for (int c2 = 1; c2 < 5; ++c2) mx = fmaxf(mx, red_lds[c2]);
      float se = 0.f;
      for (int c2 = 0; c2 < 5; ++c2) se += __expf(red_lds[c2] - mx);
      float lse = logf(se) + mx;
      for (int c2 = 0; c2 < 5; ++c2) out[c2] = red_lds[c2] - lse;
    }
  }
}

extern "C" void kernel_launch(void* const* d_in, const int* in_sizes, int n_in,
                              void* d_out, int out_size, void* d_ws, size_t ws_size,
                              hipStream_t stream) {
  (void)in_sizes; (void)n_in; (void)out_size; (void)ws_size;
  // zero the device-barrier counter region (ws is re-poisoned to 0xAA before every launch)
  hipMemsetAsync(d_ws, 0, 256, stream);
  treelstm_kernel<<<NWG, BLK, 0, stream>>>(
      (const int*)d_in[0], (const int*)d_in[1], (const float*)d_in[2],
      (const float*)d_in[3], (const float*)d_in[4], (const float*)d_in[5],
      (const float*)d_in[6], (const float*)d_in[7], (const float*)d_in[8],
      (const float*)d_in[9], (const float*)d_in[10], (const float*)d_in[11],
      (const float*)d_in[12], (const float*)d_in[13], (const float*)d_in[14],
      (const float*)d_in[15], (const float*)d_in[16], (const float*)d_in[17],
      (float*)d_ws, (float*)d_out);
}

// Round 4
// 9695.234 us; speedup vs baseline: 1.1301x; 1.0417x over previous
//
#include <hip/hip_runtime.h>
#include <hip/hip_bf16.h>

// ---------------- problem constants ----------------
constexpr int kL = 512;    // sequence length
constexpr int kD = 300;    // embedding dim
constexpr int kM = 300;    // hidden dim
constexpr int NWG = 32;    // workgroups (co-resident)
constexpr int BLK = 256;   // threads per WG
constexpr int JP = 10;     // h-indices owned per WG
constexpr int NJW = 30;    // j-owner WGs (30*10 = 300)
constexpr int NSPLIT = 6;  // k-splits per gate-row dot
constexpr int KLEN = 50;   // 300/6
constexpr int NSL = 16;    // n-slice per WG (32*16 = 512)

// ---------------- f32 workspace layout ----------------
constexpr int A_LEMB   = 1024;
constexpr int A_REMB   = A_LEMB   + kL*kD;
constexpr int A_XIOU_L = A_REMB   + kL*kD;
constexpr int A_XF_L   = A_XIOU_L + kL*900;
constexpr int A_XIOU_R = A_XF_L   + kL*300;
constexpr int A_XF_R   = A_XIOU_R + kL*900;
constexpr int A_HS_LF  = A_XF_R   + kL*300;
constexpr int A_HS_LB  = A_HS_LF  + kL*300;
constexpr int A_HS_RF  = A_HS_LB  + kL*300;
constexpr int A_HS_RB  = A_HS_RF  + kL*300;
constexpr int A_HS_L   = A_HS_RB  + kL*300;
constexpr int A_HS_R   = A_HS_L   + kL*300;
constexpr int A_TAIL   = A_HS_R   + kL*300;     // end of f32 bulk (even)

// ---------------- tagged-u64 exchange regions (u64 offsets into ws) ----------------
// PJ/PV alias the lemb/remb area (dead after prologue GEMM; fenced in between).
constexpr int U_PJ  = A_LEMB / 2;               // [2][30][4][300] hproj partials, tag=t+1
constexpr int U_PV  = U_PJ + 2*30*4*300;        // [2][32][4][300] PV partials,    tag=t+1
constexpr int U_HXA = A_TAIL / 2;               // [2][4][300]  stage-A h slots,   tag=t
constexpr int U_HXB = U_HXA + 2*4*300;          // [2][2][300]  stage-B h_att,     tag=t
constexpr int U_HP  = U_HXB + 2*2*300;          // [2][4][300]  reduced hproj,     tag=t+1
constexpr int U_DEN = U_HP  + 2*4*300;          // [2][32][4]   denom partials,    tag=t+1
constexpr int A_BFIN = (U_DEN + 2*32*4) * 2;    // f32: rh_f1, rh_b1, lh_f2, lh_b2 (1200)

__device__ __forceinline__ float fsig(float x) { return 1.0f / (1.0f + __expf(-x)); }
__device__ __forceinline__ float ftanh(float x) {
  x = fminf(fmaxf(x, -15.f), 15.f);
  float e = __expf(2.f * x);
  return (e - 1.f) / (e + 1.f);
}

__device__ __forceinline__ float aload(const float* p) {
  return __hip_atomic_load(p, __ATOMIC_RELAXED, __HIP_MEMORY_SCOPE_AGENT);
}
__device__ __forceinline__ void astore(float* p, float v) {
  __hip_atomic_store(p, v, __ATOMIC_RELAXED, __HIP_MEMORY_SCOPE_AGENT);
}
__device__ __forceinline__ unsigned long long uload(const unsigned long long* p) {
  return __hip_atomic_load(p, __ATOMIC_RELAXED, __HIP_MEMORY_SCOPE_AGENT);
}
__device__ __forceinline__ void ustore(unsigned long long* p, unsigned long long v) {
  __hip_atomic_store(p, v, __ATOMIC_RELAXED, __HIP_MEMORY_SCOPE_AGENT);
}
__device__ __forceinline__ unsigned long long pack(unsigned tag, float v) {
  return ((unsigned long long)tag << 32) | (unsigned long long)__float_as_uint(v);
}

// Heavy barrier (full fence: writes back dirty L2 so later cross-XCD normal
// reads and agent ops see plain-store data). Prologue/stage boundaries only.
__device__ __forceinline__ void gbar(unsigned* ctr, int& epoch) {
  __syncthreads();
  if (threadIdx.x == 0) {
    ++epoch;
    __threadfence();
    atomicAdd(ctr, 1u);
    const unsigned tgt = (unsigned)(NWG * epoch);
    while (__hip_atomic_load(ctr, __ATOMIC_RELAXED, __HIP_MEMORY_SCOPE_AGENT) < tgt)
      __builtin_amdgcn_s_sleep(1);
    __threadfence();
  }
  __syncthreads();
}
// Fast barrier (no cache fence) — stage boundaries where data moved agent-scope.
__device__ __forceinline__ void gbar_fast(unsigned* ctr, int& epoch) {
  __syncthreads();
  if (threadIdx.x == 0) {
    ++epoch;
    atomicAdd(ctr, 1u);
    const unsigned tgt = (unsigned)(NWG * epoch);
    while (__hip_atomic_load(ctr, __ATOMIC_RELAXED, __HIP_MEMORY_SCOPE_AGENT) < tgt)
      __builtin_amdgcn_s_sleep(1);
  }
  __syncthreads();
}

// Poll n tagged u64 from src; value i -> lds[(i/300)*304 + i%300] (304-padded rows).
__device__ __forceinline__ void poll_lds(const unsigned long long* src, float* lds,
                                         int n, unsigned tag) {
  int idx[5]; int cnt = 0;
  for (int i = threadIdx.x; i < n; i += BLK) idx[cnt++] = i;
  int rem = cnt;
  while (rem > 0) {
    #pragma unroll
    for (int q = 0; q < 5; ++q) {
      if (q < cnt && idx[q] >= 0) {
        unsigned long long v = uload(&src[idx[q]]);
        if ((unsigned)(v >> 32) == tag) {
          int i = idx[q];
          lds[(i / 300) * 304 + (i % 300)] = __uint_as_float((unsigned)v);
          idx[q] = -1; --rem;
        }
      }
    }
  }
}

__global__ __launch_bounds__(BLK) void treelstm_kernel(
    const int* __restrict__ linputs, const int* __restrict__ rinputs,
    const float* __restrict__ emb,
    const float* __restrict__ ioux_w, const float* __restrict__ ioux_b,
    const float* __restrict__ iouh_w, const float* __restrict__ iouh_b,
    const float* __restrict__ fx_w,  const float* __restrict__ fx_b,
    const float* __restrict__ fh_w,  const float* __restrict__ fh_b,
    const float* __restrict__ Wa,    const float* __restrict__ attnh_w,
    const float* __restrict__ attnh_b,
    const float* __restrict__ wh_w,  const float* __restrict__ wh_b,
    const float* __restrict__ wp_w,  const float* __restrict__ wp_b,
    float* __restrict__ ws, float* __restrict__ out) {

  __shared__ __align__(16) float h_lds[4][304];
  __shared__ __align__(16) float hpj_lds[4][304];
  __shared__ __align__(16) float part[4][40][6];   // also: part2[40][6], pf[512], hid[200]
  __shared__ float gv[4][4][10];
  __shared__ float c_lds[4][10];
  __shared__ float hnew_lds[4][10];
  __shared__ float dred[4][32];
  __shared__ __align__(16) float colsum_lds[2][300];
  __shared__ float wa_lds[300];
  __shared__ float sc_lds[4][16];
  __shared__ float red_lds[32];
  __shared__ __align__(16) __hip_bfloat16 hmp_lds[2][NSL][300];
  __shared__ __align__(16) __hip_bfloat16 hmat_lds[2][NSL][300];
  __shared__ __hip_bfloat16 a1c_lds[JP][300];

  const int wg = blockIdx.x;
  const int tid = threadIdx.x;
  const int gthread = wg * BLK + tid;
  unsigned* ctr = (unsigned*)ws;
  float* W = ws;
  unsigned long long* Ux = (unsigned long long*)ws;
  float (*part2)[6] = (float(*)[6])&part[0][0][0];
  int epoch = 0;

  // ================= K1a: embedding gather + init stage-A h(0) slot =================
  for (int i = gthread; i < 2 * kL * kD; i += NWG * BLK) {
    int side = i / (kL * kD); int r = i % (kL * kD); int t = r / kD; int d = r % kD;
    const int* idx = side ? rinputs : linputs;
    W[(side ? A_REMB : A_LEMB) + r] = emb[(long)idx[t] * kD + d];
  }
  for (int i = gthread; i < 1200; i += NWG * BLK)
    ustore(&Ux[U_HXA + i], pack(0u, 0.f));    // h(0) = 0, tag 0, slot 0
  gbar(ctr, epoch);  // heavy: flush plain emb stores

  // ================= K1b: x-projections =================
  for (int task = wg; task < 64; task += NWG) {
    int side = task & 1; int tb = task >> 1;
    float* xt = (float*)hmp_lds;
    const float* xbase = W + (side ? A_REMB : A_LEMB) + tb * 16 * kD;
    for (int i = tid; i < 16 * kD; i += BLK) xt[i] = xbase[i];
    __syncthreads();
    float* xiou = W + (side ? A_XIOU_R : A_XIOU_L) + tb * 16 * 900;
    float* xf   = W + (side ? A_XF_R   : A_XF_L)   + tb * 16 * 300;
    const float4* xt4 = (const float4*)xt;
    for (int id = tid; id < 1200; id += BLK) {
      int o4 = id >> 2, q = id & 3;
      int o0 = o4 * 4;
      float acc[4][4];
      const float* wrow[4]; float bias[4];
      #pragma unroll
      for (int m = 0; m < 4; ++m) {
        int o = o0 + m;
        if (o < 900) { wrow[m] = ioux_w + o * kD; bias[m] = ioux_b[o]; }
        else         { wrow[m] = fx_w + (o - 900) * kD; bias[m] = fx_b[o - 900]; }
        #pragma unroll
        for (int n = 0; n < 4; ++n) acc[m][n] = bias[m];
      }
      for (int k4 = 0; k4 < 75; ++k4) {
        float4 x4[4];
        #pragma unroll
        for (int n = 0; n < 4; ++n) x4[n] = xt4[(q * 4 + n) * 75 + k4];
        #pragma unroll
        for (int m = 0; m < 4; ++m) {
          float4 w4 = *(const float4*)(wrow[m] + k4 * 4);
          #pragma unroll
          for (int n = 0; n < 4; ++n)
            acc[m][n] += w4.x * x4[n].x + w4.y * x4[n].y + w4.z * x4[n].z + w4.w * x4[n].w;
        }
      }
      #pragma unroll
      for (int m = 0; m < 4; ++m) {
        int o = o0 + m;
        #pragma unroll
        for (int n = 0; n < 4; ++n) {
          int tt = q * 4 + n;
          if (o < 900) xiou[tt * 900 + o] = acc[m][n];
          else         xf[tt * 300 + (o - 900)] = acc[m][n];
        }
      }
    }
    __syncthreads();
  }
  gbar(ctr, epoch);  // heavy: flush xiou/xf (read cross-XCD with normal loads later)

  // ================= per-thread LSTM weight slices in registers =================
  float wreg[KLEN];
  int r6 = 0, s6 = 0, k0 = 0;
  if (wg < NJW && tid < 240) {
    r6 = tid / NSPLIT; s6 = tid % NSPLIT;
    int gate = r6 / JP, jl = r6 % JP, jg = wg * JP + jl;
    k0 = s6 * KLEN;
    const float* wrow = (gate < 3) ? (iouh_w + (gate * kM + jg) * kM) : (fh_w + jg * kM);
    #pragma unroll
    for (int k = 0; k < KLEN; ++k) wreg[k] = wrow[k0 + k];
  }
  float biasr = 0.f; int ach = 0, ag = 0, ajl = 0, ajg = 0;
  if (wg < NJW && tid < 160) {
    ach = tid / 40; ag = (tid / 10) % 4; ajl = tid % 10; ajg = wg * JP + ajl;
    biasr = (ag < 3) ? iouh_b[ag * kM + ajg] : fh_b[ajg];
  }
  int gch = 0, gjl = 0, gjg = 0;
  if (wg < NJW && tid < 40) { gch = tid / 10; gjl = tid % 10; gjg = wg * JP + gjl; }

  if (tid < 40) c_lds[tid / 10][tid % 10] = 0.f;
  __syncthreads();

  // ================= Stage A: 4 chains, tagged dataflow, ZERO barriers =================
  if (wg < NJW) {
    for (int t = 0; t < kL; ++t) {
      float xv = 0.f;
      if (tid < 160) {  // issue x-load early; overlaps the poll
        int trow = (ach & 1) ? (511 - t) : t;
        if (ag < 3) xv = W[(ach < 2 ? A_XIOU_L : A_XIOU_R) + trow * 900 + ag * 300 + ajg];
        else        xv = W[(ach < 2 ? A_XF_L   : A_XF_R)   + trow * 300 + ajg];
      }
      poll_lds(&Ux[U_HXA + (t & 1) * 1200], &h_lds[0][0], 1200, (unsigned)t);
      __syncthreads();
      if (tid < 240) {
        #pragma unroll
        for (int ch = 0; ch < 4; ++ch) {
          float acc = 0.f;
          #pragma unroll
          for (int k = 0; k < KLEN; ++k) acc += wreg[k] * h_lds[ch][k0 + k];
          part[ch][r6][s6] = acc;
        }
      }
      __syncthreads();
      if (tid < 160) {
        float pre = xv + biasr;
        #pragma unroll
        for (int s = 0; s < NSPLIT; ++s) pre += part[ach][ag * 10 + ajl][s];
        gv[ach][ag][ajl] = pre;
      }
      __syncthreads();
      if (tid < 40) {
        float iv = fsig(gv[gch][0][gjl]);
        float ov = fsig(gv[gch][1][gjl]);
        float uv = ftanh(gv[gch][2][gjl]);
        float fv = fsig(gv[gch][3][gjl]);
        float c = iv * uv + fv * c_lds[gch][gjl];
        c_lds[gch][gjl] = c;
        float h = ov * ftanh(c);
        ustore(&Ux[U_HXA + ((t + 1) & 1) * 1200 + gch * 300 + gjg],
               pack((unsigned)(t + 1), h));
        int hsoff = (gch == 0) ? A_HS_LF : (gch == 1) ? A_HS_LB : (gch == 2) ? A_HS_RF : A_HS_RB;
        astore(&W[hsoff + t * 300 + gjg], h);
      }
      // no barrier: next poll self-synchronizes on tag t+1
    }
  }
  gbar_fast(ctr, epoch);

  // ================= K3a: hs_l/hs_r = tanh(fwd + bwd[::-1]) =================
  for (int i = gthread; i < 2 * kL * kM; i += NWG * BLK) {
    int side = i / (kL * kM); int r = i % (kL * kM); int n = r / kM; int j = r % kM;
    float v = ftanh(W[(side ? A_HS_RF : A_HS_LF) + n * kM + j] +
                    W[(side ? A_HS_RB : A_HS_LB) + (511 - n) * kM + j]);
    astore(&W[(side ? A_HS_R : A_HS_L) + n * kM + j], v);
  }
  gbar_fast(ctr, epoch);

  // ================= K3b: attention prep =================
  for (int j = tid; j < 300; j += BLK) wa_lds[j] = Wa[j];
  if (wg < NJW)
    for (int i = tid; i < JP * 300; i += BLK) {
      int kl = i / 300, j = i % 300;
      a1c_lds[kl][j] = __float2bfloat16(attnh_w[j * 600 + wg * JP + kl]);
    }
  for (int j = tid; j < 300; j += BLK) {
    float s0 = 0.f, s1 = 0.f;
    for (int n = 0; n < kL; ++n) { s0 += W[A_HS_L + n * 300 + j]; s1 += W[A_HS_R + n * 300 + j]; }
    colsum_lds[0][j] = s0; colsum_lds[1][j] = s1;
  }
  for (int side = 0; side < 2; ++side) {
    __syncthreads();
    float* stage = (float*)hmat_lds;
    for (int i = tid; i < NSL * 300; i += BLK)
      stage[i] = W[(side ? A_HS_R : A_HS_L) + (wg * NSL) * 300 + i];
    __syncthreads();
    const float4* st4 = (const float4*)stage;
    for (int id = tid; id < 1200; id += BLK) {
      int j = id >> 2, q = id & 3;
      float b = attnh_b[j];
      float acc[4] = {b, b, b, b};
      const float* wrow = attnh_w + j * 600 + 300;
      for (int k4 = 0; k4 < 75; ++k4) {
        float4 w4 = *(const float4*)(wrow + k4 * 4);
        #pragma unroll
        for (int m = 0; m < 4; ++m) {
          float4 x4 = st4[(q * 4 + m) * 75 + k4];
          acc[m] += w4.x * x4.x + w4.y * x4.y + w4.z * x4.z + w4.w * x4.w;
        }
      }
      #pragma unroll
      for (int m = 0; m < 4; ++m) hmp_lds[side][q * 4 + m][j] = __float2bfloat16(acc[m]);
    }
  }
  __syncthreads();
  for (int i = tid; i < 2 * NSL * 300; i += BLK) {
    int side = i / (NSL * 300); int r = i % (NSL * 300);
    hmat_lds[side][r / 300][r % 300] =
        __float2bfloat16(W[(side ? A_HS_R : A_HS_L) + (wg * NSL) * 300 + r]);
  }
  if (tid < 40) c_lds[tid / 10][tid % 10] = 0.f;
  gbar_fast(ctr, epoch);

  // ================= Stage B: attention chains, tagged dataflow, ZERO barriers =================
  // ch0:(remb,hs_l) full; ch1:(lemb,hs_r) full; ch2/ch3: one step at t=0 only.
  for (int t = 0; t < kL; ++t) {
    const int nact = (t == 0) ? 4 : 2;
    const unsigned tagS = (unsigned)(t + 1);
    const int rows = nact * JP;
    const int sl = t & 1;

    if (wg < NJW) {
      // ---- D: LSTM slice ----
      float xvb = 0.f;
      if (tid < 160 && ach < nact) {
        int trow = (ach < 2) ? t : 511;
        int useL = ach & 1;
        if (ag < 3) xvb = W[(useL ? A_XIOU_L : A_XIOU_R) + trow * 900 + ag * 300 + ajg];
        else        xvb = W[(useL ? A_XF_L   : A_XF_R)   + trow * 300 + ajg];
      }
      if (t == 0) {
        for (int i = tid; i < 1216; i += BLK) ((float*)h_lds)[i] = 0.f;
      } else {
        poll_lds(&Ux[U_HXB + sl * 600], &h_lds[0][0], 600, (unsigned)t);
      }
      __syncthreads();
      if (tid < 240) {
        for (int ch = 0; ch < nact; ++ch) {
          float acc = 0.f;
          #pragma unroll
          for (int k = 0; k < KLEN; ++k) acc += wreg[k] * h_lds[ch][k0 + k];
          part[ch][r6][s6] = acc;
        }
      }
      __syncthreads();
      if (tid < 160 && ach < nact) {
        float pre = xvb + biasr;
        #pragma unroll
        for (int s = 0; s < NSPLIT; ++s) pre += part[ach][ag * 10 + ajl][s];
        gv[ach][ag][ajl] = pre;
      }
      __syncthreads();
      if (tid < 40 && gch < nact) {
        float iv = fsig(gv[gch][0][gjl]);
        float ov = fsig(gv[gch][1][gjl]);
        float uv = ftanh(gv[gch][2][gjl]);
        float fv = fsig(gv[gch][3][gjl]);
        float c = iv * uv + fv * c_lds[gch][gjl];
        c_lds[gch][gjl] = c;
        hnew_lds[gch][gjl] = ov * ftanh(c);
      }
      __syncthreads();
      // ---- PJ: per-WG hproj partial (rank-10), tagged slot ----
      for (int i = tid; i < nact * 300; i += BLK) {
        int ch = i / 300, j = i % 300;
        float acc = 0.f;
        #pragma unroll
        for (int kl = 0; kl < JP; ++kl)
          acc += hnew_lds[ch][kl] * __bfloat162float(a1c_lds[kl][j]);
        ustore(&Ux[U_PJ + sl * 36000 + wg * 1200 + ch * 300 + j], pack(tagS, acc));
      }
      // ---- reduce: sum 30 PJ slots for own 10-j slice ----
      if (tid < rows * 6) {
        int r = tid / 6, l = tid % 6;
        int ch = r / JP, jl = r % JP, jg = wg * JP + jl;
        float acc = 0.f; unsigned pend = 0x1fu;
        while (pend) {
          #pragma unroll
          for (int k = 0; k < 5; ++k) {
            if (pend & (1u << k)) {
              unsigned long long v =
                  uload(&Ux[U_PJ + sl * 36000 + (l * 5 + k) * 1200 + ch * 300 + jg]);
              if ((unsigned)(v >> 32) == tagS) {
                acc += __uint_as_float((unsigned)v);
                pend &= ~(1u << k);
              }
            }
          }
        }
        part2[r][l] = acc;
      }
      __syncthreads();
      if (tid < rows) {
        float hp = 0.f;
        #pragma unroll
        for (int l = 0; l < 6; ++l) hp += part2[tid][l];
        int ch = tid / JP, jl = tid % JP;
        ustore(&Ux[U_HP + sl * 1200 + ch * 300 + wg * JP + jl], pack(tagS, hp));
      }
    }

    // ---- score phase (ALL 32 WGs): poll reduced hproj, scores for own 16-n ----
    poll_lds(&Ux[U_HP + sl * 1200], &hpj_lds[0][0], nact * 300, tagS);
    __syncthreads();
    float* pf = &part[0][0][0];
    for (int id = tid; id < nact * NSL * 8; id += BLK) {
      int ch = id / 128; int rem = id % 128; int nl = rem / 8; int js = rem % 8;
      int side = ch & 1;
      int j0 = js * 38; int j1 = j0 + 38; if (j1 > 300) j1 = 300;
      float acc = 0.f;
      for (int j = j0; j < j1; ++j)
        acc += wa_lds[j] * ftanh(hpj_lds[ch][j] + __bfloat162float(hmp_lds[side][nl][j]));
      pf[id] = acc;
    }
    __syncthreads();
    if (tid < nact * NSL) {
      int ch = tid / NSL, nl = tid % NSL;
      float sc = 0.f;
      #pragma unroll
      for (int js = 0; js < 8; ++js) sc += pf[(ch * NSL + nl) * 8 + js];
      sc = fminf(fmaxf(sc, -60.f), 60.f);
      sc_lds[ch][nl] = __expf(sc);
    }
    __syncthreads();
    // ---- DEN + PV partials (tagged slots) ----
    if (tid < nact) {
      float dsum = 0.f;
      #pragma unroll
      for (int nl = 0; nl < NSL; ++nl) dsum += sc_lds[tid][nl];
      ustore(&Ux[U_DEN + sl * 128 + wg * 4 + tid], pack(tagS, dsum));
    }
    for (int i = tid; i < nact * 300; i += BLK) {
      int ch = i / 300, j = i % 300;
      int side = ch & 1;
      float acc = 0.f;
      #pragma unroll
      for (int nl = 0; nl < NSL; ++nl)
        acc += sc_lds[ch][nl] * __bfloat162float(hmat_lds[side][nl][j]);
      ustore(&Ux[U_PV + sl * 38400 + wg * 1200 + ch * 300 + j], pack(tagS, acc));
    }

    // ---- assemble (j-owners): h_att = h_lstm + colsum - PV/den ----
    if (wg < NJW) {
      if (tid < rows * 6) {
        int r = tid / 6, l = tid % 6;
        int ch = r / JP, jl = r % JP, jg = wg * JP + jl;
        float acc = 0.f; unsigned pend = 0u;
        #pragma unroll
        for (int k = 0; k < 6; ++k) if (l * 6 + k < 32) pend |= (1u << k);
        while (pend) {
          #pragma unroll
          for (int k = 0; k < 6; ++k) {
            if (pend & (1u << k)) {
              unsigned long long v =
                  uload(&Ux[U_PV + sl * 38400 + (l * 6 + k) * 1200 + ch * 300 + jg]);
              if ((unsigned)(v >> 32) == tagS) {
                acc += __uint_as_float((unsigned)v);
                pend &= ~(1u << k);
              }
            }
          }
        }
        part2[r][l] = acc;
      } else if (tid >= 240) {
        int q = tid - 240;
        unsigned pend = 0u;
        #pragma unroll
        for (int k = 0; k < 8; ++k) if (((q * 8 + k) & 3) < nact) pend |= (1u << k);
        while (pend) {
          #pragma unroll
          for (int k = 0; k < 8; ++k) {
            if (pend & (1u << k)) {
              int idx = q * 8 + k;
              unsigned long long v = uload(&Ux[U_DEN + sl * 128 + idx]);
              if ((unsigned)(v >> 32) == tagS) {
                dred[idx & 3][idx >> 2] = __uint_as_float((unsigned)v);
                pend &= ~(1u << k);
              }
            }
          }
        }
      }
      __syncthreads();
      if (tid < rows) {
        int ch = tid / JP, jl = tid % JP, jg = wg * JP + jl;
        float s_ = 0.f;
        #pragma unroll
        for (int l = 0; l < 6; ++l) s_ += part2[tid][l];
        float den = 0.f;
        #pragma unroll
        for (int w2 = 0; w2 < 32; ++w2) den += dred[ch][w2];
        float val = hnew_lds[ch][jl] + colsum_lds[ch & 1][jg] - s_ / den;
        if (ch < 2) {
          if (t < 511) ustore(&Ux[U_HXB + ((t + 1) & 1) * 600 + ch * 300 + jg],
                              pack((unsigned)(t + 1), val));
          else astore(&W[A_BFIN + (ch ? 600 : 0) + jg], val);   // rh_f1 / lh_f2
        } else {
          astore(&W[A_BFIN + (ch == 2 ? 300 : 900) + jg], val); // rh_b1 / lh_b2 (t==0)
        }
      }
    }
  }
  gbar_fast(ctr, epoch);

  // ================= K5: final head (WG0 only) =================
  if (wg == 0) {
    float* hl = (float*)h_lds;
    float* vec = (float*)hpj_lds;
    float* hid = &part[0][0][0];
    for (int j = tid; j < 300; j += BLK) {
      float lf = W[A_HS_LF + 511 * 300 + j] + aload(&W[A_BFIN + 600 + j]);
      float lb = W[A_HS_LB + j]             + aload(&W[A_BFIN + 900 + j]);
      float rf = aload(&W[A_BFIN + j])      + W[A_HS_RF + 511 * 300 + j];
      float rb = aload(&W[A_BFIN + 300 + j]) + W[A_HS_RB + j];
      hl[j]        = ftanh(lf);
      hl[300 + j]  = ftanh(lb);
      hl[608 + j]  = ftanh(rf);
      hl[908 + j]  = ftanh(rb);
    }
    __syncthreads();
    for (int i = tid; i < 600; i += BLK) {
      float a = hl[i], b = hl[608 + i];
      vec[i] = a * b; vec[600 + i] = fabsf(a - b);
    }
    __syncthreads();
    for (int hh = tid; hh < 200; hh += BLK) {
      float acc = wh_b[hh];
      const float* wr = wh_w + hh * 1200;
      for (int i2 = 0; i2 < 1200; ++i2) acc += wr[i2] * vec[i2];
      hid[hh] = fsig(acc);
    }
    __syncthreads();
    if (tid < 5) {
      float acc = wp_b[tid];
      const float* wr = wp_w + tid * 200;
      for (int h2 = 0; h2 < 200; ++h2) acc += wr[h2] * hid[h2];
      red_lds[tid] = acc;
    }
    __syncthreads();
    if (tid == 0) {
      float mx = red_lds[0];
      for (int c2 = 1; c2 < 5; ++c2) mx = fmaxf(mx, red_lds[c2]);
      float se = 0.f;
      for (int c2 = 0; c2 < 5; ++c2) se += __expf(red_lds[c2] - mx);
      float lse = logf(se) + mx;
      for (int c2 = 0; c2 < 5; ++c2) out[c2] = red_lds[c2] - lse;
    }
  }
}

extern "C" void kernel_launch(void* const* d_in, const int* in_sizes, int n_in,
                              void* d_out, int out_size, void* d_ws, size_t ws_size,
                              hipStream_t stream) {
  (void)in_sizes; (void)n_in; (void)out_size; (void)ws_size;
  hipMemsetAsync(d_ws, 0, 256, stream);  // barrier counter region
  treelstm_kernel<<<NWG, BLK, 0, stream>>>(
      (const int*)d_in[0], (const int*)d_in[1], (const float*)d_in[2],
      (const float*)d_in[3], (const float*)d_in[4], (const float*)d_in[5],
      (const float*)d_in[6], (const float*)d_in[7], (const float*)d_in[8],
      (const float*)d_in[9], (const float*)d_in[10], (const float*)d_in[11],
      (const float*)d_in[12], (const float*)d_in[13], (const float*)d_in[14],
      (const float*)d_in[15], (const float*)d_in[16], (const float*)d_in[17],
      (float*)d_ws, (float*)d_out);
}